// Round 8
// baseline (431.794 us; speedup 1.0000x reference)
//
#include <hip/hip_runtime.h>
#include <hip/hip_fp16.h>
#include <math.h>

#define HW 65536  // 256*256

typedef float v2f __attribute__((ext_vector_type(2), aligned(4)));
typedef _Float16 h2 __attribute__((ext_vector_type(2)));

// ---------------- K1: in_conv 1x1, 64 -> 16, fp16 out ----------------
// Weights read with wave-uniform indices -> scalar loads (SMEM pipe), no LDS.
__global__ __launch_bounds__(256) void k_inconv(const float* __restrict__ cen,
                                                const float* __restrict__ w,
                                                const float* __restrict__ bias,
                                                __half* __restrict__ xh) {
    long t  = (long)blockIdx.x * 256 + threadIdx.x;   // quad index
    long p0 = t * 4;
    int  b  = (int)(p0 >> 16);
    int  hw = (int)(p0 & 65535);

    const float4* src = (const float4*)(cen + ((long)b * 64) * HW + hw);
    float4 acc[16];
#pragma unroll
    for (int o = 0; o < 16; o++) { float bv = bias[o]; acc[o] = make_float4(bv, bv, bv, bv); }

#pragma unroll 4
    for (int i = 0; i < 64; i++) {
        float4 v = src[(long)i * (HW / 4)];
#pragma unroll
        for (int o = 0; o < 16; o++) {
            float wv = w[o * 64 + i];          // uniform -> s_load
            acc[o].x = fmaf(v.x, wv, acc[o].x);
            acc[o].y = fmaf(v.y, wv, acc[o].y);
            acc[o].z = fmaf(v.z, wv, acc[o].z);
            acc[o].w = fmaf(v.w, wv, acc[o].w);
        }
    }
#pragma unroll
    for (int o = 0; o < 16; o++) {
        __half2 lo = __floats2half2_rn(acc[o].x, acc[o].y);
        __half2 hi = __floats2half2_rn(acc[o].z, acc[o].w);
        __half2* dst = (__half2*)(xh + ((long)(b * 16 + o)) * HW + hw);
        dst[0] = lo;
        dst[1] = hi;
    }
}

// ---------------- K2: fused branch machinery (fp16-packed px stage) --------
#define CEH(a, b) { h2 _t = __builtin_elementwise_min(a, b); \
                    b = __builtin_elementwise_max(a, b); a = _t; }

__device__ __forceinline__ void sort8_h2(h2* v) {
    CEH(v[0], v[1]); CEH(v[2], v[3]); CEH(v[4], v[5]); CEH(v[6], v[7]);
    CEH(v[0], v[2]); CEH(v[1], v[3]); CEH(v[4], v[6]); CEH(v[5], v[7]);
    CEH(v[1], v[2]); CEH(v[5], v[6]); CEH(v[0], v[4]); CEH(v[3], v[7]);
    CEH(v[1], v[5]); CEH(v[2], v[6]);
    CEH(v[1], v[4]); CEH(v[3], v[6]);
    CEH(v[2], v[4]); CEH(v[3], v[5]);
    CEH(v[3], v[4]);
}
__device__ __forceinline__ void sort4_h2(h2* v) {
    CEH(v[0], v[1]); CEH(v[2], v[3]); CEH(v[0], v[2]); CEH(v[1], v[3]); CEH(v[1], v[2]);
}

#define LXS 56              // lx stride (fp32), 16B-aligned rows
#define SS  48              // lxs stride in _Float16 elements; offsets even -> b32 reads

__global__ __launch_bounds__(512, 8) void k_main(
    const __half* __restrict__ xh,
    const float* __restrict__ dw_w1, const float* __restrict__ dw_b1,
    const float* __restrict__ dw_w3, const float* __restrict__ dw_b3,
    const float* __restrict__ dw_w5, const float* __restrict__ dw_b5,
    const float* __restrict__ dw_w7, const float* __restrict__ dw_b7,
    const float* __restrict__ l1w, const float* __restrict__ l1b,
    const float* __restrict__ l2w, const float* __restrict__ l2b,
    const float* __restrict__ bw,  const float* __restrict__ bns,
    const float* __restrict__ bnb, __half* __restrict__ y16) {

    const int plane = blockIdx.y;          // b*16 + c
    const int c     = plane & 15;
    const int ty0   = (blockIdx.x >> 3) * 32;
    const int tx0   = (blockIdx.x & 7) * 32;
    const int tid   = threadIdx.x;

    __shared__ float   lx[52 * LXS];        // x tile + halo 10 (fp32)
    __shared__ _Float16 lxs[4][46 * SS];    // dw outputs (fp16, zeroed outside image)

    const __half* xp = xh + (long)plane * HW;

    // ---- stage x tile (52x52, origin (ty0-10, tx0-10)), zero outside ----
    for (int i = tid; i < 52 * 52; i += 512) {
        int r  = i / 52;
        int cc = i - r * 52;
        int gy = ty0 - 10 + r, gx = tx0 - 10 + cc;
        float v = 0.f;
        if ((unsigned)gy < 256u && (unsigned)gx < 256u) v = __half2float(xp[gy * 256 + gx]);
        lx[r * LXS + cc] = v;
    }
    __syncthreads();

    // ---- depthwise convs into lxs over 46x46 (tile + halo 7), 2-px packed ----
    const float* W7 = dw_w7 + c * 49;
    const float* W5 = dw_w5 + c * 25;
    const float* W3 = dw_w3 + c * 9;
    const float  W1 = dw_w1[c];
    const float  B1 = dw_b1[c], B3 = dw_b3[c], B5 = dw_b5[c], B7 = dw_b7[c];

    for (int u = tid; u < 46 * 23; u += 512) {   // 46 rows x 23 groups of 2 cols
        int row = u / 23;
        int pc0 = (u - row * 23) * 2;
        v2f c7 = {0, 0}, c5 = {0, 0}, c3 = {0, 0}, c1 = {0, 0};
#pragma unroll
        for (int a = 0; a < 7; a++) {
            const float* rp = &lx[(row + a) * LXS + pc0];
            v2f q0 = *(const v2f*)rp;
            v2f q1 = *(const v2f*)(rp + 2);
            v2f q2 = *(const v2f*)(rp + 4);
            v2f q3 = *(const v2f*)(rp + 6);
            float v8 = rp[8];
            float v[9] = {q0.x, q0.y, q1.x, q1.y, q2.x, q2.y, q3.x, q3.y, v8};
#pragma unroll
            for (int bb = 0; bb < 7; bb++) {
                v2f vv = {v[bb], v[bb + 1]};
                c7 += vv * W7[a * 7 + bb];
            }
            if (a >= 1 && a <= 5) {
#pragma unroll
                for (int bb = 0; bb < 5; bb++) {
                    v2f vv = {v[bb + 1], v[bb + 2]};
                    c5 += vv * W5[(a - 1) * 5 + bb];
                }
            }
            if (a >= 2 && a <= 4) {
#pragma unroll
                for (int bb = 0; bb < 3; bb++) {
                    v2f vv = {v[bb + 2], v[bb + 3]};
                    c3 += vv * W3[(a - 2) * 3 + bb];
                }
            }
            if (a == 3) {
                v2f vv = {v[3], v[4]};
                c1 = vv * W1;
            }
        }
        int gy  = ty0 - 7 + row;
        int gx0 = tx0 - 7 + pc0;
        bool rin = ((unsigned)gy < 256u);
        bool in0 = rin && ((unsigned)gx0 < 256u);
        bool in1 = rin && ((unsigned)(gx0 + 1) < 256u);
        int o = row * SS + pc0;
        v2f s;
        s.x = in0 ? c1.x + B1 : 0.f; s.y = in1 ? c1.y + B1 : 0.f;
        *(h2*)&lxs[0][o] = __builtin_convertvector(s, h2);
        s.x = in0 ? c3.x + B3 : 0.f; s.y = in1 ? c3.y + B3 : 0.f;
        *(h2*)&lxs[1][o] = __builtin_convertvector(s, h2);
        s.x = in0 ? c5.x + B5 : 0.f; s.y = in1 ? c5.y + B5 : 0.f;
        *(h2*)&lxs[2][o] = __builtin_convertvector(s, h2);
        s.x = in0 ? c7.x + B7 : 0.f; s.y = in1 ? c7.y + B7 : 0.f;
        *(h2*)&lxs[3][o] = __builtin_convertvector(s, h2);
    }
    __syncthreads();

    // ---- per-pixel machinery: one horizontal pixel PAIR per thread, fp16 ----
    const int ty  = tid >> 4;           // 0..31
    const int tx2 = (tid & 15) * 2;     // 0,2,...,30
    const int gy  = ty0 + ty, gx = tx0 + tx2;
    const int corner = ty * SS + tx2;   // lxs coords of (gy-7, gx-7)

    h2 brh[4];
#pragma unroll
    for (int i = 0; i < 4; i++) {
        const int s = 1 + 2 * i;        // 1,3,5,7
        const _Float16* xs = lxs[i];
        // offsets all even -> aligned b32 ds_reads of h2 pairs
        h2 ctr = *(const h2*)&xs[corner + 7 * SS + 7];
        h2 n0  = *(const h2*)&xs[corner + (7 - s) * SS + (7 - s)];
        h2 n1  = *(const h2*)&xs[corner + (7 - s) * SS + 7];
        h2 n2  = *(const h2*)&xs[corner + (7 - s) * SS + (7 + s)];
        h2 n3  = *(const h2*)&xs[corner + 7 * SS + (7 + s)];
        h2 n4  = *(const h2*)&xs[corner + (7 + s) * SS + (7 + s)];
        h2 n5  = *(const h2*)&xs[corner + (7 + s) * SS + 7];
        h2 n6  = *(const h2*)&xs[corner + (7 + s) * SS + (7 - s)];
        h2 n7  = *(const h2*)&xs[corner + 7 * SS + (7 - s)];

        h2 T[8];
        T[0] = ctr - n0; T[1] = ctr - n1; T[2] = ctr - n2; T[3] = ctr - n3;
        T[4] = ctr - n4; T[5] = ctr - n5; T[6] = ctr - n6; T[7] = ctr - n7;
        h2 S[4];
#pragma unroll
        for (int k = 0; k < 4; k++) S[k] = T[k] + T[k + 4];

        const _Float16 w10   = (_Float16)l1w[i * 64 + c * 4 + 0];
        const _Float16 w11   = (_Float16)l1w[i * 64 + c * 4 + 1];
        const _Float16 w12   = (_Float16)l1w[i * 64 + c * 4 + 2];
        const _Float16 w13x2 = (_Float16)(2.f * l1w[i * 64 + c * 4 + 3]);
        const _Float16 bb1   = (_Float16)l1b[i * 16 + c];

        const h2 vw10 = {w10, w10}, vw11 = {w11, w11}, vw12 = {w12, w12};
        const h2 vw13 = {w13x2, w13x2}, vbb1 = {bb1, bb1};

        h2 R[4];
#pragma unroll
        for (int m = 0; m < 4; m++) {
            h2 r = S[(m + 2) & 3] * vw12 + vbb1;
            r = S[(m + 3) & 3] * vw11 + r;
            r = S[(m + 1) & 3] * vw10 + r;
            R[m] = r;
        }

        h2 h8[8];
#pragma unroll
        for (int k = 0; k < 8; k++)
            h8[k] = (T[(k + 4) & 7] * vw13 + R[k & 3]) * T[k];
        sort8_h2(h8);

        _Float16 l2bh = (_Float16)l2b[i * 16 + c];
        h2 acc = {l2bh, l2bh};
#pragma unroll
        for (int k = 0; k < 8; k++) {
            _Float16 wh = (_Float16)l2w[i * 128 + c * 8 + k];
            h2 wv = {wh, wh};
            acc = h8[k] * wv + acc;
        }
        brh[i] = acc;
    }

    sort4_h2(brh);
    h2 yvh = {(_Float16)0.f, (_Float16)0.f};
#pragma unroll
    for (int i = 0; i < 4; i++) {
        _Float16 bwh = (_Float16)bw[c * 4 + i];
        h2 bv = {bwh, bwh};
        yvh = brh[i] * bv + yvh;
    }
    const float bsc = bns[c], bbi = bnb[c];
    float zx = fmaf((float)yvh.x, bsc, bbi);
    float zy = fmaf((float)yvh.y, bsc, bbi);
    float sx = zx / (1.f + __expf(-zx));
    float sy = zy / (1.f + __expf(-zy));
    *(__half2*)&y16[(long)plane * HW + gy * 256 + gx] = __floats2half2_rn(sx, sy);
}

// ---------------- K3: final 1x1 16 -> 1 + sigmoid ----------------
__global__ __launch_bounds__(256) void k_final(const __half* __restrict__ y16,
                                               const float* __restrict__ fw,
                                               const float* __restrict__ fb,
                                               float* __restrict__ out) {
    long t  = (long)blockIdx.x * 256 + threadIdx.x;   // pair index
    long p0 = t * 2;
    int  b  = (int)(p0 >> 16);
    int  hw = (int)(p0 & 65535);

    float accx = fb[0], accy = fb[0];
#pragma unroll
    for (int cc = 0; cc < 16; cc++) {
        __half2 h = *(const __half2*)(y16 + (long)(b * 16 + cc) * HW + hw);
        float2 v = __half22float2(h);
        float wv = fw[cc];
        accx = fmaf(v.x, wv, accx);
        accy = fmaf(v.y, wv, accy);
    }
    float2 r;
    r.x = 1.f / (1.f + __expf(-accx));
    r.y = 1.f / (1.f + __expf(-accy));
    *(float2*)(out + p0) = r;
}

extern "C" void kernel_launch(void* const* d_in, const int* in_sizes, int n_in,
                              void* d_out, int out_size, void* d_ws, size_t ws_size,
                              hipStream_t stream) {
    (void)in_sizes; (void)n_in; (void)out_size; (void)ws_size;
    const float* cen   = (const float*)d_in[0];
    // d_in[1] = mas (unused by the reference)
    const float* in_w  = (const float*)d_in[2];
    const float* in_b  = (const float*)d_in[3];
    const float* dw_w1 = (const float*)d_in[4];
    const float* dw_b1 = (const float*)d_in[5];
    const float* dw_w3 = (const float*)d_in[6];
    const float* dw_b3 = (const float*)d_in[7];
    const float* dw_w5 = (const float*)d_in[8];
    const float* dw_b5 = (const float*)d_in[9];
    const float* dw_w7 = (const float*)d_in[10];
    const float* dw_b7 = (const float*)d_in[11];
    const float* l1w   = (const float*)d_in[12];
    const float* l1b   = (const float*)d_in[13];
    const float* l2w   = (const float*)d_in[14];
    const float* l2b   = (const float*)d_in[15];
    const float* bw    = (const float*)d_in[16];
    const float* bns   = (const float*)d_in[17];
    const float* bnb   = (const float*)d_in[18];
    const float* fw    = (const float*)d_in[19];
    const float* fb    = (const float*)d_in[20];

    __half* xh  = (__half*)d_ws;                          // (8,16,256,256) fp16, 16.8 MB
    __half* y16 = xh + (size_t)8 * 16 * HW;               // (8,16,256,256) fp16, 16.8 MB
    float*  out = (float*)d_out;

    k_inconv<<<512, 256, 0, stream>>>(cen, in_w, in_b, xh);
    k_main<<<dim3(64, 128), 512, 0, stream>>>(xh, dw_w1, dw_b1, dw_w3, dw_b3,
                                              dw_w5, dw_b5, dw_w7, dw_b7,
                                              l1w, l1b, l2w, l2b, bw, bns, bnb, y16);
    k_final<<<1024, 256, 0, stream>>>(y16, fw, fb, out);
}

// Round 9
// 397.001 us; speedup vs baseline: 1.0876x; 1.0876x over previous
//
#include <hip/hip_runtime.h>
#include <hip/hip_fp16.h>
#include <math.h>

#define HW 65536          // 256*256
#define XSTRIDE 272       // 8 pad + 256 + 8 pad (fp16 elems), 544 B rows (16B aligned)
#define XPLANE (256 * XSTRIDE)

typedef float    v2f __attribute__((ext_vector_type(2), aligned(4)));
typedef float    f4  __attribute__((ext_vector_type(4)));
typedef _Float16 h2  __attribute__((ext_vector_type(2)));
typedef _Float16 h4  __attribute__((ext_vector_type(4)));

// ---------------- K1: in_conv 1x1, 64 -> 16, fp16 out ----------------
__global__ __launch_bounds__(256) void k_inconv(const float* __restrict__ cen,
                                                const float* __restrict__ w,
                                                const float* __restrict__ bias,
                                                __half* __restrict__ xh) {
    long t  = (long)blockIdx.x * 256 + threadIdx.x;   // quad index
    long p0 = t * 4;
    int  b  = (int)(p0 >> 16);
    int  hw = (int)(p0 & 65535);

    const float4* src = (const float4*)(cen + ((long)b * 64) * HW + hw);
    float4 acc[16];
#pragma unroll
    for (int o = 0; o < 16; o++) { float bv = bias[o]; acc[o] = make_float4(bv, bv, bv, bv); }

#pragma unroll 4
    for (int i = 0; i < 64; i++) {
        float4 v = src[(long)i * (HW / 4)];
#pragma unroll
        for (int o = 0; o < 16; o++) {
            float wv = w[o * 64 + i];          // wave-uniform -> s_load
            acc[o].x = fmaf(v.x, wv, acc[o].x);
            acc[o].y = fmaf(v.y, wv, acc[o].y);
            acc[o].z = fmaf(v.z, wv, acc[o].z);
            acc[o].w = fmaf(v.w, wv, acc[o].w);
        }
    }
#pragma unroll
    for (int o = 0; o < 16; o++) {
        __half2 lo = __floats2half2_rn(acc[o].x, acc[o].y);
        __half2 hi = __floats2half2_rn(acc[o].z, acc[o].w);
        __half2* dst = (__half2*)(xh + ((long)(b * 16 + o)) * HW + hw);
        dst[0] = lo;
        dst[1] = hi;
    }
}

// ---------------- K2: depthwise convs 1/3/5/7 -> padded fp16 planes --------
__global__ __launch_bounds__(256) void k_dw(
    const __half* __restrict__ xh,
    const float* __restrict__ dw_w1, const float* __restrict__ dw_b1,
    const float* __restrict__ dw_w3, const float* __restrict__ dw_b3,
    const float* __restrict__ dw_w5, const float* __restrict__ dw_b5,
    const float* __restrict__ dw_w7, const float* __restrict__ dw_b7,
    _Float16* __restrict__ xs, int cb) {

    const int pl  = blockIdx.y;          // bl*16 + c
    const int c   = pl & 15;
    const int bl  = pl >> 4;             // 0..1
    const int b   = cb * 2 + bl;
    const int ty0 = (blockIdx.x >> 3) * 32;
    const int tx0 = (blockIdx.x & 7) * 32;
    const int tid = threadIdx.x;

    __shared__ float lx[38 * 40];        // x tile + halo 3, stride 40

    const __half* xp = xh + (long)(b * 16 + c) * HW;
    for (int i = tid; i < 38 * 38; i += 256) {
        int r  = i / 38;
        int cc = i - r * 38;
        int gy = ty0 - 3 + r, gx = tx0 - 3 + cc;
        float v = 0.f;
        if ((unsigned)gy < 256u && (unsigned)gx < 256u) v = __half2float(xp[gy * 256 + gx]);
        lx[r * 40 + cc] = v;
    }
    __syncthreads();

    const float* W7 = dw_w7 + c * 49;
    const float* W5 = dw_w5 + c * 25;
    const float* W3 = dw_w3 + c * 9;
    const float  W1 = dw_w1[c];
    const float  B1 = dw_b1[c], B3 = dw_b3[c], B5 = dw_b5[c], B7 = dw_b7[c];

    const int ty  = tid >> 3;            // 0..31
    const int tx4 = (tid & 7) * 4;       // 0,4,...,28

    float a7[4] = {0, 0, 0, 0}, a5[4] = {0, 0, 0, 0};
    float a3[4] = {0, 0, 0, 0}, a1[4] = {0, 0, 0, 0};
#pragma unroll
    for (int a = 0; a < 7; a++) {
        const float4* rp = (const float4*)&lx[(ty + a) * 40 + tx4];
        float4 v0 = rp[0], v1 = rp[1], v2 = rp[2];
        float v[12] = {v0.x, v0.y, v0.z, v0.w, v1.x, v1.y, v1.z, v1.w,
                       v2.x, v2.y, v2.z, v2.w};
#pragma unroll
        for (int j = 0; j < 4; j++) {
#pragma unroll
            for (int bb = 0; bb < 7; bb++)
                a7[j] = fmaf(v[j + bb], W7[a * 7 + bb], a7[j]);
            if (a >= 1 && a <= 5) {
#pragma unroll
                for (int bb = 0; bb < 5; bb++)
                    a5[j] = fmaf(v[j + 1 + bb], W5[(a - 1) * 5 + bb], a5[j]);
            }
            if (a >= 2 && a <= 4) {
#pragma unroll
                for (int bb = 0; bb < 3; bb++)
                    a3[j] = fmaf(v[j + 2 + bb], W3[(a - 2) * 3 + bb], a3[j]);
            }
            if (a == 3) a1[j] = v[j + 3] * W1;
        }
    }

    const long pb  = (long)pl * 4;       // first plane of this (bl,c)
    const long row = (long)(ty0 + ty) * XSTRIDE + 8 + tx0 + tx4;
    f4 s;
    s = (f4){a1[0] + B1, a1[1] + B1, a1[2] + B1, a1[3] + B1};
    *(h4*)&xs[(pb + 0) * XPLANE + row] = __builtin_convertvector(s, h4);
    s = (f4){a3[0] + B3, a3[1] + B3, a3[2] + B3, a3[3] + B3};
    *(h4*)&xs[(pb + 1) * XPLANE + row] = __builtin_convertvector(s, h4);
    s = (f4){a5[0] + B5, a5[1] + B5, a5[2] + B5, a5[3] + B5};
    *(h4*)&xs[(pb + 2) * XPLANE + row] = __builtin_convertvector(s, h4);
    s = (f4){a7[0] + B7, a7[1] + B7, a7[2] + B7, a7[3] + B7};
    *(h4*)&xs[(pb + 3) * XPLANE + row] = __builtin_convertvector(s, h4);

    // zero pad columns (left 0..7, right 264..271) for the 4 branch planes
    h4 z = {(_Float16)0.f, (_Float16)0.f, (_Float16)0.f, (_Float16)0.f};
    if (tx0 == 0 && tid < 64) {
        int r  = tid >> 1;
        int cc = (tid & 1) * 4;
        long rr = (long)(ty0 + r) * XSTRIDE + cc;
#pragma unroll
        for (int i = 0; i < 4; i++) *(h4*)&xs[(pb + i) * XPLANE + rr] = z;
    }
    if (tx0 == 224 && tid < 64) {
        int r  = tid >> 1;
        int cc = 264 + (tid & 1) * 4;
        long rr = (long)(ty0 + r) * XSTRIDE + cc;
#pragma unroll
        for (int i = 0; i < 4; i++) *(h4*)&xs[(pb + i) * XPLANE + rr] = z;
    }
}

// ---------------- K3: per-pixel machinery (LDS-staged branch tiles) --------
#define CEH(a, b) { h2 _t = __builtin_elementwise_min(a, b); \
                    b = __builtin_elementwise_max(a, b); a = _t; }

__device__ __forceinline__ void sort8_h2(h2* v) {
    CEH(v[0], v[1]); CEH(v[2], v[3]); CEH(v[4], v[5]); CEH(v[6], v[7]);
    CEH(v[0], v[2]); CEH(v[1], v[3]); CEH(v[4], v[6]); CEH(v[5], v[7]);
    CEH(v[1], v[2]); CEH(v[5], v[6]); CEH(v[0], v[4]); CEH(v[3], v[7]);
    CEH(v[1], v[5]); CEH(v[2], v[6]);
    CEH(v[1], v[4]); CEH(v[3], v[6]);
    CEH(v[2], v[4]); CEH(v[3], v[5]);
    CEH(v[3], v[4]);
}
__device__ __forceinline__ void sort4_h2(h2* v) {
    CEH(v[0], v[1]); CEH(v[2], v[3]); CEH(v[0], v[2]); CEH(v[1], v[3]); CEH(v[1], v[2]);
}

#define SS 48   // staged tile stride (fp32 elems)

__global__ __launch_bounds__(512) void k_px(
    const _Float16* __restrict__ xs,
    const float* __restrict__ l1w, const float* __restrict__ l1b,
    const float* __restrict__ l2w, const float* __restrict__ l2b,
    const float* __restrict__ bw,  const float* __restrict__ bns,
    const float* __restrict__ bnb, __half* __restrict__ y16, int cb) {

    const int pl  = blockIdx.y;          // bl*16 + c
    const int c   = pl & 15;
    const int bl  = pl >> 4;
    const int b   = cb * 2 + bl;
    const int ty0 = (blockIdx.x >> 3) * 32;
    const int tx0 = (blockIdx.x & 7) * 32;
    const int tid = threadIdx.x;

    __shared__ float sxs[4][46 * SS];    // 4 branch tiles, fp32, rows gy=ty0-7+r,
                                         // cols gx=tx0-8+x  (x in [0,48))

    // ---- stage: 4 branches x 46 rows x 12 h4-segments ----
    const _Float16* base = xs + (long)pl * 4 * XPLANE;
    for (int idx = tid; idx < 4 * 46 * 12; idx += 512) {
        int br  = idx / 552;
        int rem = idx - br * 552;
        int r   = rem / 12;
        int seg = rem - r * 12;
        int gy  = ty0 - 7 + r;
        f4 val = {0.f, 0.f, 0.f, 0.f};
        if ((unsigned)gy < 256u) {
            // padded col elem = 8 + (tx0-8) + seg*4 = tx0 + seg*4  (8B aligned)
            h4 hv = *(const h4*)&base[(long)br * XPLANE + (long)gy * XSTRIDE + tx0 + seg * 4];
            val = __builtin_convertvector(hv, f4);
        }
        *(f4*)&sxs[br][r * SS + seg * 4] = val;
    }
    __syncthreads();

    // ---- px machinery: one horizontal pixel PAIR per thread ----
    const int ty  = tid >> 4;            // 0..31
    const int tx2 = (tid & 15) * 2;      // 0,2,...,30
    const int gy  = ty0 + ty, gx = tx0 + tx2;
    const int ci  = (ty + 7) * SS + tx2 + 8;   // center (even offset)

    h2 brh[4];
#pragma unroll
    for (int i = 0; i < 4; i++) {
        const int s = 1 + 2 * i;         // 1,3,5,7
        const float* xp = &sxs[i][ci];
        v2f ctr = *(const v2f*)xp;
        v2f n0  = *(const v2f*)(xp - s * SS - s);
        v2f n1  = *(const v2f*)(xp - s * SS);
        v2f n2  = *(const v2f*)(xp - s * SS + s);
        v2f n3  = *(const v2f*)(xp + s);
        v2f n4  = *(const v2f*)(xp + s * SS + s);
        v2f n5  = *(const v2f*)(xp + s * SS);
        v2f n6  = *(const v2f*)(xp + s * SS - s);
        v2f n7  = *(const v2f*)(xp - s);

        v2f T[8];
        T[0] = ctr - n0; T[1] = ctr - n1; T[2] = ctr - n2; T[3] = ctr - n3;
        T[4] = ctr - n4; T[5] = ctr - n5; T[6] = ctr - n6; T[7] = ctr - n7;
        v2f S[4];
#pragma unroll
        for (int k = 0; k < 4; k++) S[k] = T[k] + T[k + 4];

        const float w10   = l1w[i * 64 + c * 4 + 0];
        const float w11   = l1w[i * 64 + c * 4 + 1];
        const float w12   = l1w[i * 64 + c * 4 + 2];
        const float w13x2 = 2.f * l1w[i * 64 + c * 4 + 3];
        const float bb1   = l1b[i * 16 + c];

        v2f R[4];
#pragma unroll
        for (int m = 0; m < 4; m++) {
            v2f r = S[(m + 2) & 3] * w12 + bb1;
            r = S[(m + 3) & 3] * w11 + r;
            r = S[(m + 1) & 3] * w10 + r;
            R[m] = r;
        }

        h2 h8[8];
#pragma unroll
        for (int k = 0; k < 8; k++) {
            v2f o = (T[(k + 4) & 7] * w13x2 + R[k & 3]) * T[k];
            h8[k] = __builtin_convertvector(o, h2);
        }
        sort8_h2(h8);

        _Float16 l2bh = (_Float16)l2b[i * 16 + c];
        h2 acc = {l2bh, l2bh};
#pragma unroll
        for (int k = 0; k < 8; k++) {
            _Float16 wh = (_Float16)l2w[i * 128 + c * 8 + k];
            h2 wv = {wh, wh};
            acc = h8[k] * wv + acc;
        }
        brh[i] = acc;
    }

    sort4_h2(brh);
    h2 yvh = {(_Float16)0.f, (_Float16)0.f};
#pragma unroll
    for (int i = 0; i < 4; i++) {
        _Float16 bwh = (_Float16)bw[c * 4 + i];
        h2 bv = {bwh, bwh};
        yvh = brh[i] * bv + yvh;
    }
    const float bsc = bns[c], bbi = bnb[c];
    float zx = fmaf((float)yvh.x, bsc, bbi);
    float zy = fmaf((float)yvh.y, bsc, bbi);
    float sx = zx / (1.f + __expf(-zx));
    float sy = zy / (1.f + __expf(-zy));
    *(__half2*)&y16[(long)(b * 16 + c) * HW + gy * 256 + gx] = __floats2half2_rn(sx, sy);
}

// ---------------- K4: final 1x1 16 -> 1 + sigmoid ----------------
__global__ __launch_bounds__(256) void k_final(const __half* __restrict__ y16,
                                               const float* __restrict__ fw,
                                               const float* __restrict__ fb,
                                               float* __restrict__ out) {
    long t  = (long)blockIdx.x * 256 + threadIdx.x;   // pair index
    long p0 = t * 2;
    int  b  = (int)(p0 >> 16);
    int  hw = (int)(p0 & 65535);

    float accx = fb[0], accy = fb[0];
#pragma unroll
    for (int cc = 0; cc < 16; cc++) {
        __half2 h = *(const __half2*)(y16 + (long)(b * 16 + cc) * HW + hw);
        float2 v = __half22float2(h);
        float wv = fw[cc];
        accx = fmaf(v.x, wv, accx);
        accy = fmaf(v.y, wv, accy);
    }
    float2 r;
    r.x = 1.f / (1.f + __expf(-accx));
    r.y = 1.f / (1.f + __expf(-accy));
    *(float2*)(out + p0) = r;
}

extern "C" void kernel_launch(void* const* d_in, const int* in_sizes, int n_in,
                              void* d_out, int out_size, void* d_ws, size_t ws_size,
                              hipStream_t stream) {
    (void)in_sizes; (void)n_in; (void)out_size; (void)ws_size;
    const float* cen   = (const float*)d_in[0];
    // d_in[1] = mas (unused by the reference)
    const float* in_w  = (const float*)d_in[2];
    const float* in_b  = (const float*)d_in[3];
    const float* dw_w1 = (const float*)d_in[4];
    const float* dw_b1 = (const float*)d_in[5];
    const float* dw_w3 = (const float*)d_in[6];
    const float* dw_b3 = (const float*)d_in[7];
    const float* dw_w5 = (const float*)d_in[8];
    const float* dw_b5 = (const float*)d_in[9];
    const float* dw_w7 = (const float*)d_in[10];
    const float* dw_b7 = (const float*)d_in[11];
    const float* l1w   = (const float*)d_in[12];
    const float* l1b   = (const float*)d_in[13];
    const float* l2w   = (const float*)d_in[14];
    const float* l2b   = (const float*)d_in[15];
    const float* bw    = (const float*)d_in[16];
    const float* bns   = (const float*)d_in[17];
    const float* bnb   = (const float*)d_in[18];
    const float* fw    = (const float*)d_in[19];
    const float* fb    = (const float*)d_in[20];

    __half*   xh  = (__half*)d_ws;                         // 16.78 MB
    _Float16* xs  = (_Float16*)(xh + (size_t)8 * 16 * HW); // 2-batch chunk: 128 planes, 17.83 MB
    __half*   y16 = (__half*)(xs + (size_t)128 * XPLANE);  // 16.78 MB
    float*    out = (float*)d_out;

    k_inconv<<<512, 256, 0, stream>>>(cen, in_w, in_b, xh);
    for (int cb = 0; cb < 4; cb++) {
        k_dw<<<dim3(64, 32), 256, 0, stream>>>(xh, dw_w1, dw_b1, dw_w3, dw_b3,
                                               dw_w5, dw_b5, dw_w7, dw_b7, xs, cb);
        k_px<<<dim3(64, 32), 512, 0, stream>>>(xs, l1w, l1b, l2w, l2b, bw,
                                               bns, bnb, y16, cb);
    }
    k_final<<<1024, 256, 0, stream>>>(y16, fw, fb, out);
}